// Round 18
// baseline (330.212 us; speedup 1.0000x reference)
//
#include <hip/hip_runtime.h>
#include <math.h>

#define VOCABN 100
#define EMBEDN 50
#define HID 30
#define NB 512
#define NT 512
#define G4 120  // 4*HID
#define S 16    // timesteps per tick
#define RD 32   // ring depth = 2 ticks (power of 2)

#define L2E 1.44269504089f   // log2(e)
#define L2E2 2.88539008178f  // 2*log2(e)

typedef __fp16 h2v __attribute__((ext_vector_type(2)));  // matches V2h builtins

__device__ __forceinline__ float fastrcp(float x) {
  float r;
  asm("v_rcp_f32 %0, %1" : "=v"(r) : "v"(x));
  return r;
}
__device__ __forceinline__ float fexp2(float x) {
  float r;
  asm("v_exp_f32 %0, %1" : "=v"(r) : "v"(x));
  return r;
}
// v_readlane -> SGPR: uniform scalar (free broadcast operand).
__device__ __forceinline__ float rdlane(float v, int k) {
  return __builtin_bit_cast(float, __builtin_amdgcn_readlane(__builtin_bit_cast(int, v), k));
}
// Raw workgroup barrier: LDS-visibility only (lgkmcnt). Global ops stay in flight.
__device__ __forceinline__ void tick_barrier() {
  asm volatile("s_waitcnt lgkmcnt(0)" ::: "memory");
  __builtin_amdgcn_s_barrier();
  asm volatile("" ::: "memory");
}

// ---------------- prep: xpe[tok][g] = (emb[tok]@w_ih1^T + b_ih1 + b_hh1) * sc(g)
// sc(g) = 2*log2e for g-gate rows (60..89), log2e otherwise (exp2-folded).
__global__ void prep_kernel(const float* __restrict__ emb,
                            const float* __restrict__ w_ih1,
                            const float* __restrict__ b_ih1,
                            const float* __restrict__ b_hh1,
                            const float* __restrict__ b_ih2,
                            const float* __restrict__ b_hh2,
                            const float* __restrict__ lw2,
                            const float* __restrict__ lb1,
                            const float* __restrict__ lb2,
                            float* __restrict__ xpe, float* __restrict__ b2s,
                            float* __restrict__ outc) {
  __shared__ float e[EMBEDN];
  int r = blockIdx.x;
  int tid = threadIdx.x;
  if (tid < EMBEDN) e[tid] = emb[r * EMBEDN + tid];
  __syncthreads();
  if (tid < G4) {
    float s = b_ih1[tid] + b_hh1[tid];
#pragma unroll
    for (int k = 0; k < EMBEDN; ++k) s = fmaf(e[k], w_ih1[tid * EMBEDN + k], s);
    float sc = (tid >= 2 * HID && tid < 3 * HID) ? L2E2 : L2E;
    xpe[r * G4 + tid] = s * sc;
    if (r == 0) b2s[tid] = (b_ih2[tid] + b_hh2[tid]) * sc;
  }
  if (r == 0 && tid < VOCABN) {
    float o = lb2[tid];
#pragma unroll
    for (int k = 0; k < HID; ++k) o = fmaf(fmaxf(lb1[k], 0.f), lw2[tid * HID + k], o);
    outc[tid] = o;
  }
}

// 4-gate f16 recurrence step (W0/W2): lane jj owns channels' i,f,g,o rows packed
// as f16x2; dot via v_dot2_f32_f16 (f32 accum). No cross-half permlane on spine.
#define DOT4(ai, af, ag, ao, HP, W0_, W1_, W2_, W3_, I0, I1, I2, I3)  \
  float ai = (I0), af = (I1), ag = (I2), ao = (I3);                   \
  float ai1 = 0.f, af1 = 0.f, ag1 = 0.f, ao1 = 0.f;                   \
  _Pragma("unroll") for (int p = 0; p < 8; ++p) {                     \
    ai = __builtin_amdgcn_fdot2(HP[p], W0_[p], ai, false);            \
    af = __builtin_amdgcn_fdot2(HP[p], W1_[p], af, false);            \
    ag = __builtin_amdgcn_fdot2(HP[p], W2_[p], ag, false);            \
    ao = __builtin_amdgcn_fdot2(HP[p], W3_[p], ao, false);            \
  }                                                                   \
  _Pragma("unroll") for (int p = 8; p < 15; ++p) {                    \
    ai1 = __builtin_amdgcn_fdot2(HP[p], W0_[p], ai1, false);          \
    af1 = __builtin_amdgcn_fdot2(HP[p], W1_[p], af1, false);          \
    ag1 = __builtin_amdgcn_fdot2(HP[p], W2_[p], ag1, false);          \
    ao1 = __builtin_amdgcn_fdot2(HP[p], W3_[p], ao1, false);          \
  }                                                                   \
  ai += ai1; af += af1; ag += ag1; ao += ao1;

#define NONLIN_H(ai, af, ag, ao, cs, hout)                 \
  float iS = L2E2 - L2E2 * fastrcp(1.0f + fexp2(ai));      \
  float f_ = 1.0f - fastrcp(1.0f + fexp2(af));             \
  float g_ = 1.0f - 2.0f * fastrcp(1.0f + fexp2(ag));      \
  float o_ = 1.0f - fastrcp(1.0f + fexp2(ao));             \
  cs = fmaf(f_, cs, iS * g_);                              \
  float rr = fastrcp(1.0f + fexp2(cs));                    \
  float hout = fmaf(-2.0f * o_, rr, o_);

// ---------------- fused scan + head: 4 waves, S=16 steps/tick, lgkm-only barrier.
//   W0: h1[t] (4-gate f16 recurrence)  -> h1ring (f32)
//   W1: u[t] = w_ih2'.h1[t] (f32)      -> uring
//   W2: h2[t] (4-gate f16 recurrence)  -> h2ring (f32)
//   H : head MLP rows, 3 ticks behind, direct store; masked rows after last tick
__global__ void __launch_bounds__(256) scan_kernel(
    const int* __restrict__ batch_x, const int* __restrict__ lens,
    const float* __restrict__ xpe, const float* __restrict__ b2s,
    const float* __restrict__ w_hh1, const float* __restrict__ w_ih2,
    const float* __restrict__ w_hh2,
    const float* __restrict__ lw1, const float* __restrict__ lb1,
    const float* __restrict__ lw2, const float* __restrict__ lb2,
    const float* __restrict__ outc, float* __restrict__ out) {
  __shared__ __align__(16) float h1ring[RD][32];  // 4 KB
  __shared__ __align__(16) float2 uring[RD][64];  // 16 KB
  __shared__ __align__(16) float h2ring[RD][32];  // 4 KB
  __shared__ int tok_lds[NT];                     // 2 KB

  const int b = blockIdx.x;
  const int tid = threadIdx.x;
  const int wid = tid >> 6;  // 0,1,2 scan pipeline; 3 head
  const int lane = tid & 63;
  const int half = lane >> 5;
  const int j = lane & 31;
  const int jj = (j < HID) ? j : (HID - 1);

  const int* xrow = batch_x + b * NT;
  for (int i = tid; i < NT; i += 256) tok_lds[i] = xrow[i];

  const int len = lens[b];
  const int K = (len + S - 1) / S;
  __syncthreads();  // staging visible

  if (wid == 0 || wid == 2) {
    // ---------------- 4-gate f16 recurrence wave (W0: layer1, W2: layer2)
    const float* wsrc = (wid == 0) ? w_hh1 : w_hh2;
    h2v wfi[15], wff[15], wfg[15], wfo[15];
#pragma unroll
    for (int p = 0; p < 15; ++p) {
      const float* ri = wsrc + (0 * HID + jj) * HID;
      const float* rf = wsrc + (1 * HID + jj) * HID;
      const float* rg = wsrc + (2 * HID + jj) * HID;
      const float* ro = wsrc + (3 * HID + jj) * HID;
      wfi[p] = __builtin_amdgcn_cvt_pkrtz(ri[2 * p] * L2E, ri[2 * p + 1] * L2E);
      wff[p] = __builtin_amdgcn_cvt_pkrtz(rf[2 * p] * L2E, rf[2 * p + 1] * L2E);
      wfg[p] = __builtin_amdgcn_cvt_pkrtz(rg[2 * p] * L2E2, rg[2 * p + 1] * L2E2);
      wfo[p] = __builtin_amdgcn_cvt_pkrtz(ro[2 * p] * L2E, ro[2 * p + 1] * L2E);
    }
    h2v hp[15];
#pragma unroll
    for (int p = 0; p < 15; ++p) hp[p] = h2v{(__fp16)0.0f, (__fp16)0.0f};
    float cs = 0.f;

    if (wid == 0) {
      // xpe prefetch, 2-deep, 4 gate-values per step
      int tk = tok_lds[0];
      float x0i = xpe[tk * G4 + jj], x0f = xpe[tk * G4 + HID + jj];
      float x0g = xpe[tk * G4 + 2 * HID + jj], x0o = xpe[tk * G4 + 3 * HID + jj];
      tk = tok_lds[1];
      float x1i = xpe[tk * G4 + jj], x1f = xpe[tk * G4 + HID + jj];
      float x1g = xpe[tk * G4 + 2 * HID + jj], x1o = xpe[tk * G4 + 3 * HID + jj];
      int t = 0;
      for (int k = 0; k < K + 3; ++k) {
        if (k < K) {
          int tend = (k + 1) * S;
          tend = (tend < len) ? tend : len;
          for (; t < tend; ++t) {
            DOT4(ai, af, ag, ao, hp, wfi, wff, wfg, wfo, x0i, x0f, x0g, x0o)
            NONLIN_H(ai, af, ag, ao, cs, h1n)
            if (lane < 32) h1ring[t & (RD - 1)][j] = h1n;
#pragma unroll
            for (int q = 0; q < 15; ++q)
              hp[q] = __builtin_amdgcn_cvt_pkrtz(rdlane(h1n, 2 * q),
                                                 rdlane(h1n, 2 * q + 1));
            x0i = x1i; x0f = x1f; x0g = x1g; x0o = x1o;
            int tn = t + 2;
            tk = tok_lds[(tn < NT) ? tn : (NT - 1)];
            x1i = xpe[tk * G4 + jj];
            x1f = xpe[tk * G4 + HID + jj];
            x1g = xpe[tk * G4 + 2 * HID + jj];
            x1o = xpe[tk * G4 + 3 * HID + jj];
          }
        }
        tick_barrier();
      }
    } else {
      // W2: gate accumulators seeded from u (W1 output, 2-gate layout) + bias
      const float b2i = b2s[jj], b2f = b2s[HID + jj];
      const float b2g = b2s[2 * HID + jj], b2o = b2s[3 * HID + jj];
      int t = 0;
      for (int k = 0; k < K + 3; ++k) {
        if (k >= 2) {
          int tend = (k - 1) * S;
          tend = (tend < len) ? tend : len;
          for (; t < tend; ++t) {
            float2 uif = uring[t & (RD - 1)][jj];       // (i,f) partials
            float2 ugo = uring[t & (RD - 1)][jj + 32];  // (g,o) partials
            DOT4(ai, af, ag, ao, hp, wfi, wff, wfg, wfo,
                 uif.x + b2i, uif.y + b2f, ugo.x + b2g, ugo.y + b2o)
            NONLIN_H(ai, af, ag, ao, cs, h2n)
            if (lane < 32) h2ring[t & (RD - 1)][j] = h2n;
#pragma unroll
            for (int q = 0; q < 15; ++q)
              hp[q] = __builtin_amdgcn_cvt_pkrtz(rdlane(h2n, 2 * q),
                                                 rdlane(h2n, 2 * q + 1));
          }
        }
        tick_barrier();
      }
    }
  } else if (wid == 1) {
    // ---------------- W1: u[t] = w_ih2' . h1[t], f32, 2-gate layout
    // half0 lane j: (i_j, f_j) -> uring[t][j]; half1 lane j: (g_j, o_j) -> uring[t][j+32]
    const int gA = half ? (jj + 2 * HID) : jj;
    const int gB = gA + HID;
    const float scA = half ? L2E2 : L2E;
    float wA[HID], wB[HID];
#pragma unroll
    for (int k = 0; k < HID; ++k) {
      wA[k] = w_ih2[gA * HID + k] * scA;
      wB[k] = w_ih2[gB * HID + k] * L2E;
    }
    int t = 0;
    for (int k = 0; k < K + 3; ++k) {
      if (k >= 1 && k <= K) {
        int tend = k * S;
        tend = (tend < len) ? tend : len;
        for (; t < tend; ++t) {
          const float2* hpd = (const float2*)h1ring[t & (RD - 1)];
          float2 hv[15];
#pragma unroll
          for (int p = 0; p < 15; ++p) hv[p] = hpd[p];
          float q0a = 0.f, q0b = 0.f, q1a = 0.f, q1b = 0.f;
#pragma unroll
          for (int p = 0; p < 15; ++p) {
            if (p < 8) {
              q0a = fmaf(hv[p].x, wA[2 * p], q0a);
              q1a = fmaf(hv[p].x, wB[2 * p], q1a);
              q0a = fmaf(hv[p].y, wA[2 * p + 1], q0a);
              q1a = fmaf(hv[p].y, wB[2 * p + 1], q1a);
            } else {
              q0b = fmaf(hv[p].x, wA[2 * p], q0b);
              q1b = fmaf(hv[p].x, wB[2 * p], q1b);
              q0b = fmaf(hv[p].y, wA[2 * p + 1], q0b);
              q1b = fmaf(hv[p].y, wB[2 * p + 1], q1b);
            }
          }
          float2 u;
          u.x = q0a + q0b;  // half0: i-partial ; half1: g-partial
          u.y = q1a + q1b;  // half0: f-partial ; half1: o-partial
          uring[t & (RD - 1)][lane] = u;
        }
      }
      tick_barrier();
    }
  } else {
    // ---------------- H: head MLP, 3 ticks behind, reads h2ring, stores out
    const int l1 = (lane < 50) ? lane : 49;
    float w1x[15], w1y[15];
#pragma unroll
    for (int p = 0; p < 15; ++p) {
      w1x[p] = lw1[jj * HID + 2 * p];
      w1y[p] = lw1[jj * HID + 2 * p + 1];
    }
    float w2a[HID], w2b[HID];
#pragma unroll
    for (int k = 0; k < HID; ++k) {
      w2a[k] = lw2[l1 * HID + k];
      w2b[k] = lw2[(l1 + 50) * HID + k];
    }
    const float lb1v = lb1[jj];
    const float lb2a = lb2[l1], lb2b = lb2[l1 + 50];
    const float oca = outc[l1], ocb = outc[l1 + 50];

    int t = 0;
    for (int k = 0; k < K + 3; ++k) {
      if (k >= 3) {
        int tend = (k - 2) * S;
        tend = (tend < len) ? tend : len;
        for (; t < tend; ++t) {
          const float2* hpd = (const float2*)h2ring[t & (RD - 1)];
          float2 h[15];
#pragma unroll
          for (int p = 0; p < 15; ++p) h[p] = hpd[p];
          float ma = lb1v, mb = 0.f;
#pragma unroll
          for (int p = 0; p < 15; ++p) {
            if (p < 8) {
              ma = fmaf(h[p].x, w1x[p], ma);
              ma = fmaf(h[p].y, w1y[p], ma);
            } else {
              mb = fmaf(h[p].x, w1x[p], mb);
              mb = fmaf(h[p].y, w1y[p], mb);
            }
          }
          float m = fmaxf(ma + mb, 0.f);
          float sm[HID];
#pragma unroll
          for (int q = 0; q < HID; ++q) sm[q] = rdlane(m, q);
          float oa0 = lb2a, oa1 = 0.f, ob0 = lb2b, ob1 = 0.f;
#pragma unroll
          for (int q = 0; q < 15; ++q) {
            oa0 = fmaf(sm[q], w2a[q], oa0);
            ob0 = fmaf(sm[q], w2b[q], ob0);
            oa1 = fmaf(sm[q + 15], w2a[q + 15], oa1);
            ob1 = fmaf(sm[q + 15], w2b[q + 15], ob1);
          }
          float* orow = out + ((size_t)(b * NT + t)) * VOCABN;
          if (lane < 50) {
            orow[l1] = oa0 + oa1;
            orow[l1 + 50] = ob0 + ob1;
          }
        }
      }
      tick_barrier();
    }
    for (int tt = len; tt < NT; ++tt) {
      float* orow = out + ((size_t)(b * NT + tt)) * VOCABN;
      if (lane < 50) {
        orow[l1] = oca;
        orow[l1 + 50] = ocb;
      }
    }
  }
}

extern "C" void kernel_launch(void* const* d_in, const int* in_sizes, int n_in,
                              void* d_out, int out_size, void* d_ws, size_t ws_size,
                              hipStream_t stream) {
  const int* batch_x = (const int*)d_in[0];
  const int* lens = (const int*)d_in[1];
  const float* emb = (const float*)d_in[2];
  const float* w_ih1 = (const float*)d_in[3];
  const float* w_hh1 = (const float*)d_in[4];
  const float* b_ih1 = (const float*)d_in[5];
  const float* b_hh1 = (const float*)d_in[6];
  const float* w_ih2 = (const float*)d_in[7];
  const float* w_hh2 = (const float*)d_in[8];
  const float* b_ih2 = (const float*)d_in[9];
  const float* b_hh2 = (const float*)d_in[10];
  const float* lw1 = (const float*)d_in[11];
  const float* lb1 = (const float*)d_in[12];
  const float* lw2 = (const float*)d_in[13];
  const float* lb2 = (const float*)d_in[14];
  float* out = (float*)d_out;

  char* ws = (char*)d_ws;
  float* xpe = (float*)ws;                 // 100*120 floats (exp2-scaled)
  float* b2s = (float*)(ws + 48 * 1024);   // 120 floats (exp2-scaled)
  float* outc = (float*)(ws + 56 * 1024);  // 100 floats

  prep_kernel<<<VOCABN, 128, 0, stream>>>(emb, w_ih1, b_ih1, b_hh1, b_ih2, b_hh2,
                                          lw2, lb1, lb2, xpe, b2s, outc);
  scan_kernel<<<NB, 256, 0, stream>>>(batch_x, lens, xpe, b2s, w_hh1, w_ih2, w_hh2,
                                      lw1, lb1, lw2, lb2, outc, out);
}

// Round 19
// 266.732 us; speedup vs baseline: 1.2380x; 1.2380x over previous
//
#include <hip/hip_runtime.h>
#include <math.h>

#define VOCABN 100
#define EMBEDN 50
#define HID 30
#define NB 512
#define NT 512
#define G4 120  // 4*HID
#define S 8     // timesteps per tick
#define RD 16   // ring depth = 2 ticks (power of 2)

__device__ __forceinline__ float fastrcp(float x) {
  float r;
  asm("v_rcp_f32 %0, %1" : "=v"(r) : "v"(x));
  return r;
}
__device__ __forceinline__ float tanh_fast(float x) {
  return 1.0f - 2.0f * fastrcp(1.0f + __expf(2.0f * x));
}
// v_permlane32_swap(x,x): lo_all = lanes[0..31]'s value in all lanes, hi_all = lanes[32..63]'s.
__device__ __forceinline__ void bcast_halves(float x, float& lo_all, float& hi_all) {
  auto r = __builtin_amdgcn_permlane32_swap(__builtin_bit_cast(unsigned, x),
                                            __builtin_bit_cast(unsigned, x), false, false);
  lo_all = __builtin_bit_cast(float, (unsigned)r[0]);
  hi_all = __builtin_bit_cast(float, (unsigned)r[1]);
}
// v_readlane -> SGPR: uniform scalars (free broadcast operand of v_fmac).
__device__ __forceinline__ float rdlane(float v, int k) {
  return __builtin_bit_cast(float, __builtin_amdgcn_readlane(__builtin_bit_cast(int, v), k));
}
// Raw workgroup barrier: LDS-visibility only (lgkmcnt). Global ops stay in flight.
__device__ __forceinline__ void tick_barrier() {
  asm volatile("s_waitcnt lgkmcnt(0)" ::: "memory");
  __builtin_amdgcn_s_barrier();
  asm volatile("" ::: "memory");
}

// ---------------- prep: xpe[tok][g] = emb[tok]@w_ih1^T + b_ih1 + b_hh1 ; b2s = b_ih2+b_hh2
// also outc[v] = lb2[v] + relu(lb1) . lw2[v]  (output row for masked timesteps)
__global__ void prep_kernel(const float* __restrict__ emb,
                            const float* __restrict__ w_ih1,
                            const float* __restrict__ b_ih1,
                            const float* __restrict__ b_hh1,
                            const float* __restrict__ b_ih2,
                            const float* __restrict__ b_hh2,
                            const float* __restrict__ lw2,
                            const float* __restrict__ lb1,
                            const float* __restrict__ lb2,
                            float* __restrict__ xpe, float* __restrict__ b2s,
                            float* __restrict__ outc) {
  __shared__ float e[EMBEDN];
  int r = blockIdx.x;
  int tid = threadIdx.x;
  if (tid < EMBEDN) e[tid] = emb[r * EMBEDN + tid];
  __syncthreads();
  if (tid < G4) {
    float s = b_ih1[tid] + b_hh1[tid];
#pragma unroll
    for (int k = 0; k < EMBEDN; ++k) s = fmaf(e[k], w_ih1[tid * EMBEDN + k], s);
    xpe[r * G4 + tid] = s;
    if (r == 0) b2s[tid] = b_ih2[tid] + b_hh2[tid];
  }
  if (r == 0 && tid < VOCABN) {
    float o = lb2[tid];
#pragma unroll
    for (int k = 0; k < HID; ++k) o = fmaf(fmaxf(lb1[k], 0.f), lw2[tid * HID + k], o);
    outc[tid] = o;
  }
}

// ---------------- fused scan + head: 4 waves per sequence, S=8 steps/tick,
// lgkm-only barrier per tick.
//   W0 tick k: h1[t], t in [kS,(k+1)S)        -> h1ring
//   W1 tick k: u[t]=w_ih2.h1[t], t in [(k-1)S,kS)
//   W2 tick k: h2[t], t in [(k-2)S,(k-1)S)    -> h2ring (LDS only; no global h2)
//   H  tick k: out rows [(k-3)S,(k-2)S)  (head MLP from h2ring; direct store)
// After the last barrier H writes the precomputed constant row for t >= len.
__global__ void __launch_bounds__(256) scan_kernel(
    const int* __restrict__ batch_x, const int* __restrict__ lens,
    const float* __restrict__ xpe, const float* __restrict__ b2s,
    const float* __restrict__ w_hh1, const float* __restrict__ w_ih2,
    const float* __restrict__ w_hh2,
    const float* __restrict__ lw1, const float* __restrict__ lb1,
    const float* __restrict__ lw2, const float* __restrict__ lb2,
    const float* __restrict__ outc, float* __restrict__ out) {
  __shared__ __align__(16) float h1ring[RD][32];  // 2 KB
  __shared__ __align__(16) float2 uring[RD][64];  // 8 KB
  __shared__ __align__(16) float h2ring[RD][32];  // 2 KB
  __shared__ int tok_lds[NT];                     // 2 KB

  const int b = blockIdx.x;
  const int tid = threadIdx.x;
  const int wid = tid >> 6;  // 0,1,2 = scan pipeline; 3 = head
  const int lane = tid & 63;
  const int half = lane >> 5;
  const int j = lane & 31;
  const int jj = (j < HID) ? j : (HID - 1);
  // half0 lane j: gates (i_j, f_j); half1 lane j: gates (g_j, o_j)
  const int gA = half ? (jj + 2 * HID) : jj;
  const int gB = gA + HID;
  const float bg = half ? 2.0f : 1.0f;  // beta: 1 -> sigmoid, 2 -> tanh

  const int* xrow = batch_x + b * NT;
  for (int i = tid; i < NT; i += 256) tok_lds[i] = xrow[i];

  const int len = lens[b];
  const int K = (len + S - 1) / S;
  __syncthreads();  // staging visible

  if (wid < 3) {
    // per-wave weight slice: rows gA,gB of this wave's matrix (60 VGPR, resident)
    const float* wsrc = (wid == 0) ? w_hh1 : (wid == 1) ? w_ih2 : w_hh2;
    float wA[HID], wB[HID];
#pragma unroll
    for (int k = 0; k < HID; ++k) {
      wA[k] = wsrc[gA * HID + k];
      wB[k] = wsrc[gB * HID + k];
    }
    const float b2A = b2s[gA], b2B = b2s[gB];

    if (wid == 0) {
      // ---------------- W0: layer-1 recurrence, state in SGPRs, 3-deep xpe pipeline
      float c1 = 0.f;
      float hs1[HID];
#pragma unroll
      for (int k = 0; k < HID; ++k) hs1[k] = 0.f;
      int tk = tok_lds[0];
      float xa0 = xpe[tk * G4 + gA], xb0 = xpe[tk * G4 + gB];
      tk = tok_lds[1];
      float xa1 = xpe[tk * G4 + gA], xb1 = xpe[tk * G4 + gB];
      tk = tok_lds[2];
      float xa2 = xpe[tk * G4 + gA], xb2 = xpe[tk * G4 + gB];
      int t = 0;
      for (int k = 0; k < K + 3; ++k) {
        if (k < K) {
          int tend = (k + 1) * S;
          tend = (tend < len) ? tend : len;
          for (; t < tend; ++t) {
            float a0a = 0.f, a0b = 0.f, a1a = 0.f, a1b = 0.f;
#pragma unroll
            for (int p = 0; p < 15; ++p) {
              a0a = fmaf(hs1[p], wA[p], a0a);
              a1a = fmaf(hs1[p], wB[p], a1a);
              a0b = fmaf(hs1[p + 15], wA[p + 15], a0b);
              a1b = fmaf(hs1[p + 15], wB[p + 15], a1b);
            }
            float a0 = a0a + a0b + xa0;
            float a1 = a1a + a1b + xb0;
            float sA = 1.0f - bg * fastrcp(1.0f + __expf(bg * a0));
            float sB = 1.0f - fastrcp(1.0f + __expf(a1));
            float i1, g1, f1, o1;
            bcast_halves(sA, i1, g1);
            bcast_halves(sB, f1, o1);
            c1 = fmaf(f1, c1, i1 * g1);
            float h1n = o1 * tanh_fast(c1);
            if (lane < 32) h1ring[t & (RD - 1)][j] = h1n;
#pragma unroll
            for (int q = 0; q < HID; ++q) hs1[q] = rdlane(h1n, q);
            xa0 = xa1; xb0 = xb1;
            xa1 = xa2; xb1 = xb2;
            int tn = t + 3;
            tk = tok_lds[(tn < NT) ? tn : (NT - 1)];
            xa2 = xpe[tk * G4 + gA];
            xb2 = xpe[tk * G4 + gB];
          }
        }
        tick_barrier();
      }
    } else if (wid == 1) {
      // ---------------- W1: u[t] = w_ih2 . h1[t]  (independent steps -> deep ILP)
      int t = 0;
      for (int k = 0; k < K + 3; ++k) {
        if (k >= 1 && k <= K) {
          int tend = k * S;
          tend = (tend < len) ? tend : len;
          for (; t < tend; ++t) {
            const float2* hp = (const float2*)h1ring[t & (RD - 1)];
            float2 hv[15];
#pragma unroll
            for (int p = 0; p < 15; ++p) hv[p] = hp[p];
            float q0a = 0.f, q0b = 0.f, q1a = 0.f, q1b = 0.f;
#pragma unroll
            for (int p = 0; p < 15; ++p) {
              if (p < 8) {
                q0a = fmaf(hv[p].x, wA[2 * p], q0a);
                q1a = fmaf(hv[p].x, wB[2 * p], q1a);
                q0a = fmaf(hv[p].y, wA[2 * p + 1], q0a);
                q1a = fmaf(hv[p].y, wB[2 * p + 1], q1a);
              } else {
                q0b = fmaf(hv[p].x, wA[2 * p], q0b);
                q1b = fmaf(hv[p].x, wB[2 * p], q1b);
                q0b = fmaf(hv[p].y, wA[2 * p + 1], q0b);
                q1b = fmaf(hv[p].y, wB[2 * p + 1], q1b);
              }
            }
            float2 u;
            u.x = q0a + q0b;
            u.y = q1a + q1b;
            uring[t & (RD - 1)][lane] = u;
          }
        }
        tick_barrier();
      }
    } else {
      // ---------------- W2: layer-2 recurrence -> h2ring (LDS only)
      float c2 = 0.f;
      float hs2[HID];
#pragma unroll
      for (int k = 0; k < HID; ++k) hs2[k] = 0.f;
      int t = 0;
      for (int k = 0; k < K + 3; ++k) {
        if (k >= 2) {
          int tend = (k - 1) * S;
          tend = (tend < len) ? tend : len;
          for (; t < tend; ++t) {
            float2 u = uring[t & (RD - 1)][lane];
            float q0a = 0.f, q0b = 0.f, q1a = 0.f, q1b = 0.f;
#pragma unroll
            for (int p = 0; p < 15; ++p) {
              q0a = fmaf(hs2[p], wA[p], q0a);
              q1a = fmaf(hs2[p], wB[p], q1a);
              q0b = fmaf(hs2[p + 15], wA[p + 15], q0b);
              q1b = fmaf(hs2[p + 15], wB[p + 15], q1b);
            }
            float q0 = q0a + q0b + u.x + b2A;
            float q1 = q1a + q1b + u.y + b2B;
            float uA = 1.0f - bg * fastrcp(1.0f + __expf(bg * q0));
            float uB = 1.0f - fastrcp(1.0f + __expf(q1));
            float i2, g2, f2, o2;
            bcast_halves(uA, i2, g2);
            bcast_halves(uB, f2, o2);
            c2 = fmaf(f2, c2, i2 * g2);
            float h2n = o2 * tanh_fast(c2);
            if (lane < 32) h2ring[t & (RD - 1)][j] = h2n;
#pragma unroll
            for (int q = 0; q < HID; ++q) hs2[q] = rdlane(h2n, q);
          }
        }
        tick_barrier();
      }
    }
  } else {
    // ---------------- H: head MLP, 3 ticks behind W0, reads h2ring, stores out.
    const int l1 = (lane < 50) ? lane : 49;  // vocab cols l1, l1+50
    float w1x[15], w1y[15];
#pragma unroll
    for (int p = 0; p < 15; ++p) {
      w1x[p] = lw1[jj * HID + 2 * p];
      w1y[p] = lw1[jj * HID + 2 * p + 1];
    }
    float w2a[HID], w2b[HID];
#pragma unroll
    for (int k = 0; k < HID; ++k) {
      w2a[k] = lw2[l1 * HID + k];
      w2b[k] = lw2[(l1 + 50) * HID + k];
    }
    const float lb1v = lb1[jj];
    const float lb2a = lb2[l1], lb2b = lb2[l1 + 50];
    const float oca = outc[l1], ocb = outc[l1 + 50];

    int t = 0;
    for (int k = 0; k < K + 3; ++k) {
      if (k >= 3) {
        int tend = (k - 2) * S;
        tend = (tend < len) ? tend : len;
        for (; t < tend; ++t) {
          const float2* hp = (const float2*)h2ring[t & (RD - 1)];  // broadcast reads
          float2 h[15];
#pragma unroll
          for (int p = 0; p < 15; ++p) h[p] = hp[p];
          float ma = lb1v, mb = 0.f;
#pragma unroll
          for (int p = 0; p < 15; ++p) {
            if (p < 8) {
              ma = fmaf(h[p].x, w1x[p], ma);
              ma = fmaf(h[p].y, w1y[p], ma);
            } else {
              mb = fmaf(h[p].x, w1x[p], mb);
              mb = fmaf(h[p].y, w1y[p], mb);
            }
          }
          float m = fmaxf(ma + mb, 0.f);
          float sm[HID];
#pragma unroll
          for (int q = 0; q < HID; ++q) sm[q] = rdlane(m, q);
          float oa0 = lb2a, oa1 = 0.f, ob0 = lb2b, ob1 = 0.f;
#pragma unroll
          for (int q = 0; q < 15; ++q) {
            oa0 = fmaf(sm[q], w2a[q], oa0);
            ob0 = fmaf(sm[q], w2b[q], ob0);
            oa1 = fmaf(sm[q + 15], w2a[q + 15], oa1);
            ob1 = fmaf(sm[q + 15], w2b[q + 15], ob1);
          }
          float* orow = out + ((size_t)(b * NT + t)) * VOCABN;
          if (lane < 50) {
            orow[l1] = oa0 + oa1;
            orow[l1 + 50] = ob0 + ob1;
          }
        }
      }
      tick_barrier();
    }
    // masked rows t >= len: constant row (no barriers past this point)
    for (int tt = len; tt < NT; ++tt) {
      float* orow = out + ((size_t)(b * NT + tt)) * VOCABN;
      if (lane < 50) {
        orow[l1] = oca;
        orow[l1 + 50] = ocb;
      }
    }
  }
}

extern "C" void kernel_launch(void* const* d_in, const int* in_sizes, int n_in,
                              void* d_out, int out_size, void* d_ws, size_t ws_size,
                              hipStream_t stream) {
  const int* batch_x = (const int*)d_in[0];
  const int* lens = (const int*)d_in[1];
  const float* emb = (const float*)d_in[2];
  const float* w_ih1 = (const float*)d_in[3];
  const float* w_hh1 = (const float*)d_in[4];
  const float* b_ih1 = (const float*)d_in[5];
  const float* b_hh1 = (const float*)d_in[6];
  const float* w_ih2 = (const float*)d_in[7];
  const float* w_hh2 = (const float*)d_in[8];
  const float* b_ih2 = (const float*)d_in[9];
  const float* b_hh2 = (const float*)d_in[10];
  const float* lw1 = (const float*)d_in[11];
  const float* lb1 = (const float*)d_in[12];
  const float* lw2 = (const float*)d_in[13];
  const float* lb2 = (const float*)d_in[14];
  float* out = (float*)d_out;

  char* ws = (char*)d_ws;
  float* xpe = (float*)ws;                 // 100*120 floats
  float* b2s = (float*)(ws + 48 * 1024);   // 120 floats
  float* outc = (float*)(ws + 56 * 1024);  // 100 floats

  prep_kernel<<<VOCABN, 128, 0, stream>>>(emb, w_ih1, b_ih1, b_hh1, b_ih2, b_hh2,
                                          lw2, lb1, lb2, xpe, b2s, outc);
  scan_kernel<<<NB, 256, 0, stream>>>(batch_x, lens, xpe, b2s, w_hh1, w_ih2, w_hh2,
                                      lw1, lb1, lw2, lb2, outc, out);
}